// Round 7
// baseline (179.973 us; speedup 1.0000x reference)
//
#include <hip/hip_runtime.h>
#include <hip/hip_bf16.h>
#include <hip/hip_fp16.h>

#define BS 8
#define C  256
#define N  9216
#define E  9215
#define MAXD 128               // off[] bins; actual depth <= 64 (6 doubling iters)
#define LVL_STRIDE 192         // per-batch ints in lvlOff: [0..128]=offsets, [129]=maxd
#define TSLABS (N / 64)        // 144 transpose slabs per batch

// ---------------------------------------------------------------------------
// Kernel 1: transpose emb [b][c][n] fp32 -> embT [b][n][c] fp16. Runs alone
// (levels moved to kernel 2 so it no longer serializes behind the transpose).
// ---------------------------------------------------------------------------
__global__ __launch_bounds__(1024) void transpose_kernel(const float* __restrict__ emb,
                                                         __half* __restrict__ embT) {
    const int tb = blockIdx.x;
    const int b  = tb & 7;            // batch fastest -> spreads XCD traffic
    const int n0 = (tb >> 3) * 64;
    __shared__ __half tile[256][65];  // 33.3 KB
    const int tid = threadIdx.x;

    const int nn = tid & 63;
    const int cg = tid >> 6;          // 16 channel groups of 16
    const float* src = emb + (size_t)b * C * N + n0;
    #pragma unroll
    for (int k = 0; k < 16; ++k) {
        int cc = cg * 16 + k;
        tile[cc][nn] = __float2half(src[(size_t)cc * N + nn]);
    }
    __syncthreads();

    const int cp = tid & 127;         // channel-pair index (0..127)
    const int ng = tid >> 7;          // 8 node groups of 8
    __half* dst = embT + ((size_t)b * N + n0) * C;
    #pragma unroll
    for (int k = 0; k < 8; ++k) {
        int n2 = ng * 8 + k;
        __half2 v = __halves2half2(tile[2 * cp][n2], tile[2 * cp + 1][n2]);
        *(__half2*)(dst + (size_t)n2 * C + 2 * cp) = v;
    }
}

// ---------------------------------------------------------------------------
// Kernel 2 (fused): blocks [0,8) = per-batch level schedule (LDS-heavy, no
// global BW to speak of); blocks [8,...) = edge weights (global-BW-heavy, no
// LDS use) -> complementary roles share the machine well.
//
// Levels improvements vs R6: ping-pong doubling (6 barriers), single
// family-size atomic phase with 8x sub-counters (contention /8), parallel
// Hillis-Steele scan instead of the serial 128-bin loop.
// ---------------------------------------------------------------------------
__global__ __launch_bounds__(1024) void wl_kernel(const __half* __restrict__ embT,
                                                  const int* __restrict__ tree,
                                                  float* __restrict__ wgt,
                                                  int* __restrict__ uparr,
                                                  unsigned char* __restrict__ lenG,
                                                  int* __restrict__ lvlOff) {
    __shared__ int P[N];              // anc|dep<<16 -> (dep<<25|sub<<22|lo) -> (dep<<25|base)
    __shared__ int Q[N];              // doubling ping-pong buffer, then child counts
    __shared__ int cnt8[MAXD * 8];    // 8 sub-counters per level
    __shared__ int tot[MAXD];
    __shared__ int sc1[MAXD];
    __shared__ int off[MAXD + 1];
    __shared__ int maxd_sh;
    const int tid = threadIdx.x;

    if (blockIdx.x >= BS) {
        // ---- weights role: 32 lanes per edge, float4 loads of fp16 vectors ----
        const int wb = blockIdx.x - BS;
        const int b  = wb & 7;
        const int l  = tid & 31;
        const int e  = (wb >> 3) * 32 + (tid >> 5);
        if (e < E) {
            int s = tree[(b * E + e) * 2];
            int t = tree[(b * E + e) * 2 + 1];
            const float4* ps = (const float4*)(embT + ((size_t)b * N + s) * C) + l;
            const float4* pt = (const float4*)(embT + ((size_t)b * N + t) * C) + l;
            float4 av = *ps;
            float4 bv = *pt;
            const __half2* ah = (const __half2*)&av;
            const __half2* bh = (const __half2*)&bv;
            float acc = 0.f;
            #pragma unroll
            for (int j = 0; j < 4; ++j) {
                float2 fa = __half22float2(ah[j]);
                float2 fb = __half22float2(bh[j]);
                float d0 = fa.x - fb.x;
                float d1 = fa.y - fb.y;
                acc += d0 * d0 + d1 * d1;
            }
            #pragma unroll
            for (int m = 16; m >= 1; m >>= 1) acc += __shfl_xor(acc, m);
            if (l == 0) wgt[b * N + e] = __expf(-0.01f * acc);
        }
        return;
    }

    // ---- levels role ----
    const int b = blockIdx.x;
    const int* tb = tree + b * E * 2;

    // phase 1: init P, zero sub-counters and lenG (coalesced int writes)
    for (int t = tid; t < N; t += 1024)
        P[t] = (t == 0) ? 0 : (tb[(t - 1) * 2] | (1 << 16));
    for (int i = tid; i < MAXD * 8; i += 1024) cnt8[i] = 0;
    {
        int* lz = (int*)(lenG + b * N);
        for (int i = tid; i < N / 4; i += 1024) lz[i] = 0;
    }
    if (tid == 0) maxd_sh = 1;
    __syncthreads();

    // phase 2: packed pointer doubling, ping-pong P<->Q (dep <= 64 after 6)
    for (int r = 0; r < 3; ++r) {
        for (int t = tid; t < N; t += 1024) {
            int p = P[t];
            int pa = P[p & 0xffff];
            Q[t] = (pa & 0xffff) | (((p >> 16) + (pa >> 16)) << 16);
        }
        __syncthreads();
        for (int t = tid; t < N; t += 1024) {
            int p = Q[t];
            int pa = Q[p & 0xffff];
            P[t] = (pa & 0xffff) | (((p >> 16) + (pa >> 16)) << 16);
        }
        __syncthreads();
    }

    // phase 3: child counts into Q
    for (int t = tid; t < N; t += 1024) Q[t] = 0;
    __syncthreads();
    for (int t = 1 + tid; t < N; t += 1024) atomicAdd(&Q[tb[(t - 1) * 2]], 1);
    __syncthreads();

    // phase 4: per-parent slot reservation in (level, sub) bins
    for (int p = tid; p < N; p += 1024) {
        int c = Q[p];
        int dep = P[p] >> 16;          // <= 64
        if (c > 0) {
            int dlev = dep + 1;
            int sub = tid >> 7;        // 8 subs
            int lo = atomicAdd(&cnt8[dlev * 8 + sub], c);
            P[p] = (dep << 25) | (sub << 22) | lo;   // lo <= 9214 fits 14 bits
        } else {
            P[p] = (dep << 25);
        }
    }
    __syncthreads();

    // phase 5: sub-scan within each level (thread d handles level d) + totals
    for (int d = tid; d < MAXD; d += 1024) {
        int s = 0;
        #pragma unroll
        for (int k = 0; k < 8; ++k) {
            int v = cnt8[d * 8 + k];
            cnt8[d * 8 + k] = s;
            s += v;
        }
        tot[d] = s;
        if (s > 0) atomicMax(&maxd_sh, d);
    }
    __syncthreads();

    // phase 6: Hillis-Steele inclusive scan over 128 level totals -> off
    {
        int* src = tot; int* dst = sc1;
        for (int step = 1; step < MAXD; step <<= 1) {
            for (int d = tid; d < MAXD; d += 1024)
                dst[d] = src[d] + ((d >= step) ? src[d - step] : 0);
            __syncthreads();
            int* tmp = src; src = dst; dst = tmp;
        }
        for (int d = tid; d < MAXD; d += 1024) off[d + 1] = src[d];
        if (tid == 0) off[0] = 0;
    }
    __syncthreads();

    // phase 7: per-parent base + head bytes (chunk len<=2, atomic flag if >2)
    for (int p = tid; p < N; p += 1024) {
        int c = Q[p];
        if (c > 0) {
            int v = P[p];
            int dep = ((unsigned)v) >> 25;
            int sub = (v >> 22) & 7;
            int lo  = v & 0x3FFF;
            int dlev = dep + 1;
            int base = off[dlev] + cnt8[dlev * 8 + sub] + lo;
            P[p] = (dep << 25) | base;
            unsigned char fl = (c > 2) ? 4 : 0;
            for (int j = 0; j < c; j += 2)
                lenG[b * N + base + j] = (unsigned char)(((j + 2 <= c) ? 2 : 1) | fl);
        }
    }
    __syncthreads();

    // phase 8: scatter children into family-contiguous slots
    for (int t = 1 + tid; t < N; t += 1024) {
        int p = tb[(t - 1) * 2];
        unsigned int o = atomicSub((unsigned int*)&Q[p], 1u) - 1u;
        int slot = (P[p] & 0x3FFF) + (int)o;
        uparr[b * N + slot] = t | (p << 16);
    }
    for (int i = tid; i <= MAXD; i += 1024) lvlOff[b * LVL_STRIDE + i] = off[i];
    if (tid == 0) lvlOff[b * LVL_STRIDE + MAXD + 1] = maxd_sh;
}

// ---------------------------------------------------------------------------
// Kernel 3: LDS-resident tree DP with register software-pipelining: next
// level's static (TSW, LEN, off) are prefetched into registers before the
// barrier, so the per-level critical chain is only V[t]-read -> V[p]-RMW.
// LDS: V 72K + TSW 72K + LEN 9K + off ~0.5K = ~154 KB.
// ---------------------------------------------------------------------------
#define UP_PROCESS(e0, e1, lb)                                                \
    if (lb) {                                                                 \
        int p_ = (e0).x >> 16;                                                \
        float w0_ = __int_as_float((e0).y);                                   \
        float2 v0_ = V[(e0).x & 0xffff];                                      \
        float ax_ = w0_ * v0_.x, ay_ = w0_ * v0_.y;                           \
        if ((lb) & 2) {                                                       \
            float w1_ = __int_as_float((e1).y);                               \
            float2 v1_ = V[(e1).x & 0xffff];                                  \
            ax_ += w1_ * v1_.x; ay_ += w1_ * v1_.y;                           \
        }                                                                     \
        if ((lb) & 4) { atomicAdd(&V[p_].x, ax_); atomicAdd(&V[p_].y, ay_); } \
        else { float2 vp_ = V[p_]; V[p_] = make_float2(vp_.x + ax_, vp_.y + ay_); } \
    }

#define DOWN_PROCESS(g)                                                       \
    {                                                                         \
        int t_ = (g).x & 0xffff, s_ = (g).x >> 16;                            \
        float w_ = __int_as_float((g).y);                                     \
        float2 vs_ = V[s_], vt_ = V[t_];                                      \
        float c_ = 1.f - w_ * w_;                                             \
        V[t_] = make_float2(w_ * vs_.x + c_ * vt_.x, w_ * vs_.y + c_ * vt_.y); \
    }

__global__ __launch_bounds__(1024) void dp_kernel(const float* __restrict__ feat,
                                                  const int* __restrict__ lvlOff,
                                                  const int* __restrict__ uparr,
                                                  const unsigned char* __restrict__ lenG,
                                                  const float* __restrict__ wgt,
                                                  float* __restrict__ out) {
    const int b = blockIdx.x;
    const int tid = threadIdx.x;
    __shared__ float2 V[N];                          // (F, G)
    __shared__ int2 TSW[N];                          // (child|parent<<16, w bits)
    __shared__ __align__(16) unsigned char LEN[N];   // head bytes
    __shared__ int off[MAXD + 1];
    __shared__ int maxd_s;

    for (int i = tid; i <= MAXD; i += 1024) off[i] = lvlOff[b * LVL_STRIDE + i];
    if (tid == 0) maxd_s = lvlOff[b * LVL_STRIDE + MAXD + 1];

    const int* tsA = uparr + b * N;
    const float* wG = wgt + b * N;
    const int* lG4 = (const int*)(lenG + b * N);
    for (int i = tid; i < N; i += 1024)
        V[i] = make_float2(feat[b * N + i], 1.0f);
    for (int i = tid; i < N / 4; i += 1024)
        ((int*)LEN)[i] = lG4[i];
    for (int i = tid; i < E; i += 1024) {            // pipelined w gather
        int ts = tsA[i];
        float w = wG[(ts & 0xffff) - 1];
        TSW[i] = make_int2(ts, __float_as_int(w));
    }
    __syncthreads();
    const int maxd = maxd_s;

    // ---- up pass (deepest level first), 1-level register pipeline ----
    int s1 = off[maxd + 1];
    int s0 = off[maxd];
    int pns0 = (maxd >= 2) ? off[maxd - 1] : 0;
    int2 eA0, eA1, eB0, eB1; int lbA, lbB;
    {
        int i0 = s0 + tid, i1 = i0 + 1024;
        int c0 = (i0 < s1) ? i0 : 0;
        int c1 = (i1 < s1) ? i1 : 0;
        lbA = (i0 < s1) ? LEN[c0] : 0;
        lbB = (i1 < s1) ? LEN[c1] : 0;
        eA0 = TSW[c0]; eA1 = TSW[c0 + 1];
        eB0 = TSW[c1]; eB1 = TSW[c1 + 1];
    }
    for (int lev = maxd; lev >= 1; --lev) {
        int ns0 = pns0, ns1 = s0;
        pns0 = (lev >= 2) ? off[lev - 2] : 0;
        int2 fA0, fA1, fB0, fB1; int nlbA = 0, nlbB = 0;
        fA0 = fA1 = fB0 = fB1 = make_int2(0, 0);
        if (lev > 1) {
            int i0 = ns0 + tid, i1 = i0 + 1024;
            int c0 = (i0 < ns1) ? i0 : 0;
            int c1 = (i1 < ns1) ? i1 : 0;
            nlbA = (i0 < ns1) ? LEN[c0] : 0;
            nlbB = (i1 < ns1) ? LEN[c1] : 0;
            fA0 = TSW[c0]; fA1 = TSW[c0 + 1];
            fB0 = TSW[c1]; fB1 = TSW[c1 + 1];
        }
        UP_PROCESS(eA0, eA1, lbA);
        UP_PROCESS(eB0, eB1, lbB);
        for (int i = s0 + tid + 2048; i < s1; i += 1024) {   // cold fallback
            int lb = LEN[i];
            int2 g0 = TSW[i]; int2 g1 = TSW[i + 1];
            UP_PROCESS(g0, g1, lb);
        }
        __syncthreads();
        s0 = ns0; s1 = ns1;
        eA0 = fA0; eA1 = fA1; eB0 = fB0; eB1 = fB1; lbA = nlbA; lbB = nlbB;
    }

    // ---- down pass (root to leaf), same pipeline ----
    int d0 = off[1], d1 = off[2];
    bool vA, vB; int2 gA, gB;
    {
        int i0 = d0 + tid, i1 = i0 + 1024;
        vA = i0 < d1; vB = i1 < d1;
        gA = TSW[vA ? i0 : 0]; gB = TSW[vB ? i1 : 0];
    }
    for (int lev = 1; lev <= maxd; ++lev) {
        int nd0 = d1;
        int nd1 = off[(lev + 2 <= MAXD) ? lev + 2 : MAXD];
        bool nvA = false, nvB = false; int2 hA = gA, hB = gB;
        if (lev < maxd) {
            int i0 = nd0 + tid, i1 = i0 + 1024;
            nvA = i0 < nd1; nvB = i1 < nd1;
            hA = TSW[nvA ? i0 : 0]; hB = TSW[nvB ? i1 : 0];
        }
        if (vA) DOWN_PROCESS(gA);
        if (vB) DOWN_PROCESS(gB);
        for (int i = d0 + tid + 2048; i < d1; i += 1024) {   // cold fallback
            int2 g = TSW[i];
            DOWN_PROCESS(g);
        }
        __syncthreads();
        d0 = nd0; d1 = nd1; vA = nvA; vB = nvB; gA = hA; gB = hB;
    }

    for (int i = tid; i < N; i += 1024) {
        float2 v = V[i];
        out[b * N + i] = v.x / v.y;
    }
}

extern "C" void kernel_launch(void* const* d_in, const int* in_sizes, int n_in,
                              void* d_out, int out_size, void* d_ws, size_t ws_size,
                              hipStream_t stream) {
    const float* feat = (const float*)d_in[0];   // [8,1,96,96]
    const float* emb  = (const float*)d_in[1];   // [8,256,96,96]
    const int*   tree = (const int*)d_in[2];     // [8,9215,2]
    float* out = (float*)d_out;                  // [8,1,96,96]

    const size_t BN = (size_t)BS * N;
    float* wgt    = (float*)d_ws;                           // BN f32 (edge order)
    int*   uparr  = (int*)((char*)d_ws + BN * 4);           // BN i32 ((lvl,family) order)
    int*   lvlOff = (int*)((char*)d_ws + BN * 8);           // BS*LVL_STRIDE i32
    unsigned char* lenG = (unsigned char*)((char*)d_ws + BN * 8 + BS * LVL_STRIDE * 4);
    __half* embT  = (__half*)((char*)d_ws +
                     ((BN * 9 + BS * LVL_STRIDE * 4 + 255) / 256) * 256);  // BS*N*C fp16

    transpose_kernel<<<TSLABS * BS, 1024, 0, stream>>>(emb, embT);
    wl_kernel<<<BS + ((E + 31) / 32) * BS, 1024, 0, stream>>>(embT, tree, wgt, uparr, lenG, lvlOff);
    dp_kernel<<<BS, 1024, 0, stream>>>(feat, lvlOff, uparr, lenG, wgt, out);
}

// Round 8
// 171.223 us; speedup vs baseline: 1.0511x; 1.0511x over previous
//
#include <hip/hip_runtime.h>
#include <hip/hip_bf16.h>
#include <hip/hip_fp16.h>

#define BS 8
#define C  256
#define N  9216
#define E  9215
#define MAXD 128               // off[] bins; actual depth <= 64 (6 doubling iters)
#define LVL_STRIDE 192         // per-batch ints: [0..128]=off, 129=maxd, 130=loEnd, 131=hiStart
#define TSLABS (N / 64)        // 144 transpose slabs per batch
#define NARROW 64              // level-size threshold for single-wave processing

// ---------------------------------------------------------------------------
// Kernel 1 (fused): blocks [0,8) = per-batch level schedule; blocks [8,1160)
// = transpose emb [b][c][n] fp32 -> embT [b][n][c] fp16. Levels' 8 blocks
// hide under transpose's 1152. Transpose tile overlays levels' P[] in LDS.
// Levels emits: uparr (child|parent<<16, family-contiguous within levels),
// lenG head bytes (chunk len<=2 | atomic flag), off[] and narrow/wide markers.
// ---------------------------------------------------------------------------
__global__ __launch_bounds__(1024) void setup_kernel(const float* __restrict__ emb,
                                                     __half* __restrict__ embT,
                                                     const int* __restrict__ tree,
                                                     int* __restrict__ uparr,
                                                     unsigned char* __restrict__ lenG,
                                                     int* __restrict__ lvlOff) {
    __shared__ int P[N];              // anc|dep<<16 -> (dep<<25|sub<<22|lo) -> (dep<<25|base)
    __shared__ int Q[N];              // doubling ping-pong, then child counts
    __shared__ int cnt8[MAXD * 8];    // 8 sub-counters per level
    __shared__ int tot[MAXD];
    __shared__ int sc1[MAXD];
    __shared__ int off[MAXD + 1];
    __shared__ int maxd_sh;
    const int tid = threadIdx.x;

    if (blockIdx.x >= BS) {
        // ---- transpose role: 64 nodes x 256 channels per block ----
        const int tb = blockIdx.x - BS;
        const int b  = tb & 7;            // batch fastest -> spreads XCD traffic
        const int n0 = (tb >> 3) * 64;
        __half (*tile)[65] = (__half(*)[65])P;   // 33.3 KB < P's 36 KB

        const int nn = tid & 63;
        const int cg = tid >> 6;          // 16 channel groups of 16
        const float* src = emb + (size_t)b * C * N + n0;
        #pragma unroll
        for (int k = 0; k < 16; ++k) {
            int cc = cg * 16 + k;
            tile[cc][nn] = __float2half(src[(size_t)cc * N + nn]);
        }
        __syncthreads();

        const int cp = tid & 127;         // channel-pair index (0..127)
        const int ng = tid >> 7;          // 8 node groups of 8
        __half* dst = embT + ((size_t)b * N + n0) * C;
        #pragma unroll
        for (int k = 0; k < 8; ++k) {
            int n2 = ng * 8 + k;
            __half2 v = __halves2half2(tile[2 * cp][n2], tile[2 * cp + 1][n2]);
            *(__half2*)(dst + (size_t)n2 * C + 2 * cp) = v;
        }
        return;
    }

    // ---- levels role ----
    const int b = blockIdx.x;
    const int* tb = tree + b * E * 2;

    // phase 1: init P, zero sub-counters and lenG (coalesced int writes)
    for (int t = tid; t < N; t += 1024)
        P[t] = (t == 0) ? 0 : (tb[(t - 1) * 2] | (1 << 16));
    for (int i = tid; i < MAXD * 8; i += 1024) cnt8[i] = 0;
    {
        int* lz = (int*)(lenG + b * N);
        for (int i = tid; i < N / 4; i += 1024) lz[i] = 0;
    }
    if (tid == 0) maxd_sh = 1;
    __syncthreads();

    // phase 2: packed pointer doubling, ping-pong P<->Q (dep <= 64 after 6)
    for (int r = 0; r < 3; ++r) {
        for (int t = tid; t < N; t += 1024) {
            int p = P[t];
            int pa = P[p & 0xffff];
            Q[t] = (pa & 0xffff) | (((p >> 16) + (pa >> 16)) << 16);
        }
        __syncthreads();
        for (int t = tid; t < N; t += 1024) {
            int p = Q[t];
            int pa = Q[p & 0xffff];
            P[t] = (pa & 0xffff) | (((p >> 16) + (pa >> 16)) << 16);
        }
        __syncthreads();
    }

    // phase 3: child counts into Q
    for (int t = tid; t < N; t += 1024) Q[t] = 0;
    __syncthreads();
    for (int t = 1 + tid; t < N; t += 1024) atomicAdd(&Q[tb[(t - 1) * 2]], 1);
    __syncthreads();

    // phase 4: per-parent slot reservation in (level, sub) bins
    for (int p = tid; p < N; p += 1024) {
        int c = Q[p];
        int dep = P[p] >> 16;          // <= 64
        if (c > 0) {
            int dlev = dep + 1;
            int sub = tid >> 7;        // 8 subs -> contention /8
            int lo = atomicAdd(&cnt8[dlev * 8 + sub], c);
            P[p] = (dep << 25) | (sub << 22) | lo;   // lo <= 9214 fits 14 bits
        } else {
            P[p] = (dep << 25);
        }
    }
    __syncthreads();

    // phase 5: sub-scan within each level (thread d handles level d) + totals
    for (int d = tid; d < MAXD; d += 1024) {
        int s = 0;
        #pragma unroll
        for (int k = 0; k < 8; ++k) {
            int v = cnt8[d * 8 + k];
            cnt8[d * 8 + k] = s;
            s += v;
        }
        tot[d] = s;
        if (s > 0) atomicMax(&maxd_sh, d);
    }
    __syncthreads();

    // phase 6: Hillis-Steele inclusive scan over 128 level totals -> off
    {
        int* src = tot; int* dst = sc1;
        for (int step = 1; step < MAXD; step <<= 1) {
            for (int d = tid; d < MAXD; d += 1024)
                dst[d] = src[d] + ((d >= step) ? src[d - step] : 0);
            __syncthreads();
            int* tmp = src; src = dst; dst = tmp;
        }
        for (int d = tid; d < MAXD; d += 1024) off[d + 1] = src[d];
        if (tid == 0) off[0] = 0;
    }
    __syncthreads();

    // phase 7: per-parent base + head bytes; thread 0 also emits metadata
    if (tid == 0) {
        int md = maxd_sh;
        int lo = 0;
        while (lo < md && off[lo + 2] - off[lo + 1] <= NARROW) ++lo;
        int hi = md + 1;
        while (hi > lo + 1 && off[hi] - off[hi - 1] <= NARROW) --hi;
        lvlOff[b * LVL_STRIDE + 129] = md;
        lvlOff[b * LVL_STRIDE + 130] = lo;
        lvlOff[b * LVL_STRIDE + 131] = hi;
    }
    for (int p = tid; p < N; p += 1024) {
        int c = Q[p];
        if (c > 0) {
            int v = P[p];
            int dep = ((unsigned)v) >> 25;
            int sub = (v >> 22) & 7;
            int lo  = v & 0x3FFF;
            int dlev = dep + 1;
            int base = off[dlev] + cnt8[dlev * 8 + sub] + lo;
            P[p] = (dep << 25) | base;
            unsigned char fl = (c > 2) ? 4 : 0;
            for (int j = 0; j < c; j += 2)
                lenG[b * N + base + j] = (unsigned char)(((j + 2 <= c) ? 2 : 1) | fl);
        }
    }
    __syncthreads();

    // phase 8: scatter children into family-contiguous slots
    for (int t = 1 + tid; t < N; t += 1024) {
        int p = tb[(t - 1) * 2];
        unsigned int o = atomicSub((unsigned int*)&Q[p], 1u) - 1u;
        int slot = (P[p] & 0x3FFF) + (int)o;
        uparr[b * N + slot] = t | (p << 16);
    }
    for (int i = tid; i <= MAXD; i += 1024) lvlOff[b * LVL_STRIDE + i] = off[i];
}

// ---------------------------------------------------------------------------
// Kernel 2: edge weights from node-major fp16. 32 lanes per edge, float4 loads.
// ---------------------------------------------------------------------------
__global__ __launch_bounds__(256) void weights_kernel(const __half* __restrict__ embT,
                                                      const int* __restrict__ tree,
                                                      float* __restrict__ wgt) {
    const int b   = blockIdx.y;
    const int tid = threadIdx.x;
    const int lane = tid & 63;
    const int wid  = tid >> 6;
    const int sub  = lane >> 5;
    const int l    = lane & 31;
    const int e    = (blockIdx.x * 4 + wid) * 2 + sub;

    float acc = 0.f;
    if (e < E) {
        int s = tree[(b * E + e) * 2];
        int t = tree[(b * E + e) * 2 + 1];
        const float4* ps = (const float4*)(embT + ((size_t)b * N + s) * C) + l;
        const float4* pt = (const float4*)(embT + ((size_t)b * N + t) * C) + l;
        float4 av = *ps;
        float4 bv = *pt;
        const __half2* ah = (const __half2*)&av;
        const __half2* bh = (const __half2*)&bv;
        #pragma unroll
        for (int j = 0; j < 4; ++j) {
            float2 fa = __half22float2(ah[j]);
            float2 fb = __half22float2(bh[j]);
            float d0 = fa.x - fb.x;
            float d1 = fa.y - fb.y;
            acc += d0 * d0 + d1 * d1;
        }
    }
    #pragma unroll
    for (int m = 16; m >= 1; m >>= 1) acc += __shfl_xor(acc, m);
    if (l == 0 && e < E) wgt[b * N + e] = __expf(-0.01f * acc);
}

// ---------------------------------------------------------------------------
// Kernel 3: LDS-resident tree DP. 512 threads (8 waves -> cheaper barriers).
// Narrow levels (<=64 edges: the top ~2 and bottom ~15 of each tree) are
// processed entirely by wave 0 with only s_waitcnt fences between levels --
// intra-wave DS ops are in-order, so no __syncthreads needed. Wide middle
// levels use all 512 threads + barrier. LDS ~157 KB -> 1 block/CU.
// ---------------------------------------------------------------------------
__device__ __forceinline__ void up_slot(float2* V, const int2* TSW,
                                        const unsigned char* LEN, int i) {
    int lb = LEN[i];
    if (lb) {
        int2 e0 = TSW[i];
        int p = e0.x >> 16;
        float w0 = __int_as_float(e0.y);
        float2 v0 = V[e0.x & 0xffff];
        float ax = w0 * v0.x, ay = w0 * v0.y;
        if (lb & 2) {
            int2 e1 = TSW[i + 1];
            float w1 = __int_as_float(e1.y);
            float2 v1 = V[e1.x & 0xffff];
            ax += w1 * v1.x; ay += w1 * v1.y;
        }
        if (lb & 4) {
            atomicAdd(&V[p].x, ax);
            atomicAdd(&V[p].y, ay);
        } else {
            float2 vp = V[p];
            V[p] = make_float2(vp.x + ax, vp.y + ay);
        }
    }
}

__device__ __forceinline__ void down_slot(float2* V, const int2* TSW, int i) {
    int2 g = TSW[i];
    int t = g.x & 0xffff, s = g.x >> 16;
    float w = __int_as_float(g.y);
    float2 vs = V[s], vt = V[t];
    float c = 1.f - w * w;
    V[t] = make_float2(w * vs.x + c * vt.x, w * vs.y + c * vt.y);
}

__global__ __launch_bounds__(512) void dp_kernel(const float* __restrict__ feat,
                                                 const int* __restrict__ lvlOff,
                                                 const int* __restrict__ uparr,
                                                 const unsigned char* __restrict__ lenG,
                                                 const float* __restrict__ wgt,
                                                 float* __restrict__ out) {
    const int b = blockIdx.x;
    const int tid = threadIdx.x;
    __shared__ float2 V[N];                          // (F, G)
    __shared__ int2 TSW[N];                          // (child|parent<<16, w bits)
    __shared__ __align__(16) unsigned char LEN[N];   // head bytes
    __shared__ int off[MAXD + 1];
    __shared__ int meta[3];                          // maxd, loEnd, hiStart

    for (int i = tid; i <= MAXD; i += 512) off[i] = lvlOff[b * LVL_STRIDE + i];
    if (tid < 3) meta[tid] = lvlOff[b * LVL_STRIDE + 129 + tid];

    const int* tsA = uparr + b * N;
    const float* wG = wgt + b * N;
    for (int i = tid; i < N; i += 512)
        V[i] = make_float2(feat[b * N + i], 1.0f);
    {
        const int* lG4 = (const int*)(lenG + b * N);
        for (int i = tid; i < N / 4; i += 512) ((int*)LEN)[i] = lG4[i];
    }
    for (int i = tid; i < E; i += 512) {             // pipelined w gather
        int ts = tsA[i];
        float w = wG[(ts & 0xffff) - 1];
        TSW[i] = make_int2(ts, __float_as_int(w));
    }
    __syncthreads();
    const int maxd = meta[0], loE = meta[1], hiS = meta[2];

    // ---- up pass (deepest level first) ----
    if (tid < 64) {                                  // narrow deep tail: wave 0
        for (int lev = maxd; lev >= hiS; --lev) {
            int s0 = off[lev], s1 = off[lev + 1];
            for (int i = s0 + tid; i < s1; i += 64) up_slot(V, TSW, LEN, i);
            __threadfence_block();
        }
    }
    __syncthreads();
    for (int lev = hiS - 1; lev > loE; --lev) {      // wide middle: all waves
        int s0 = off[lev], s1 = off[lev + 1];
        for (int i = s0 + tid; i < s1; i += 512) up_slot(V, TSW, LEN, i);
        __syncthreads();
    }
    if (tid < 64) {                                  // narrow top: wave 0
        for (int lev = loE; lev >= 1; --lev) {
            int s0 = off[lev], s1 = off[lev + 1];
            for (int i = s0 + tid; i < s1; i += 64) up_slot(V, TSW, LEN, i);
            __threadfence_block();
        }
    }
    __syncthreads();

    // ---- down pass (root to leaf) ----
    if (tid < 64) {                                  // narrow top: wave 0
        for (int lev = 1; lev <= loE; ++lev) {
            int s0 = off[lev], s1 = off[lev + 1];
            for (int i = s0 + tid; i < s1; i += 64) down_slot(V, TSW, i);
            __threadfence_block();
        }
    }
    __syncthreads();
    for (int lev = loE + 1; lev < hiS; ++lev) {      // wide middle: all waves
        int s0 = off[lev], s1 = off[lev + 1];
        for (int i = s0 + tid; i < s1; i += 512) down_slot(V, TSW, i);
        __syncthreads();
    }
    if (tid < 64) {                                  // narrow deep tail: wave 0
        for (int lev = hiS; lev <= maxd; ++lev) {
            int s0 = off[lev], s1 = off[lev + 1];
            for (int i = s0 + tid; i < s1; i += 64) down_slot(V, TSW, i);
            __threadfence_block();
        }
    }
    __syncthreads();

    for (int i = tid; i < N; i += 512) {
        float2 v = V[i];
        out[b * N + i] = v.x / v.y;
    }
}

extern "C" void kernel_launch(void* const* d_in, const int* in_sizes, int n_in,
                              void* d_out, int out_size, void* d_ws, size_t ws_size,
                              hipStream_t stream) {
    const float* feat = (const float*)d_in[0];   // [8,1,96,96]
    const float* emb  = (const float*)d_in[1];   // [8,256,96,96]
    const int*   tree = (const int*)d_in[2];     // [8,9215,2]
    float* out = (float*)d_out;                  // [8,1,96,96]

    const size_t BN = (size_t)BS * N;
    float* wgt    = (float*)d_ws;                           // BN f32 (edge order)
    int*   uparr  = (int*)((char*)d_ws + BN * 4);           // BN i32 ((lvl,family) order)
    int*   lvlOff = (int*)((char*)d_ws + BN * 8);           // BS*LVL_STRIDE i32
    unsigned char* lenG = (unsigned char*)((char*)d_ws + BN * 8 + BS * LVL_STRIDE * 4);
    __half* embT  = (__half*)((char*)d_ws +
                     ((BN * 9 + BS * LVL_STRIDE * 4 + 255) / 256) * 256);  // BS*N*C fp16

    setup_kernel<<<BS + TSLABS * BS, 1024, 0, stream>>>(emb, embT, tree, uparr, lenG, lvlOff);
    weights_kernel<<<dim3((E + 7) / 8, BS), 256, 0, stream>>>(embT, tree, wgt);
    dp_kernel<<<BS, 512, 0, stream>>>(feat, lvlOff, uparr, lenG, wgt, out);
}